// Round 2
// baseline (31155.121 us; speedup 1.0000x reference)
//
#include <hip/hip_runtime.h>
#include <hip/hip_bf16.h>

// Problem constants
#define HH    1024
#define DD    256
#define BSB   1024
#define TT    256
#define N3H   3072   // 3*H
#define CAT1  32
#define CAT2E 47

typedef unsigned short u16;
typedef short bf16x8 __attribute__((ext_vector_type(8)));
typedef float f32x4  __attribute__((ext_vector_type(4)));

__device__ __forceinline__ u16 f2bf(float f) {
  // round-to-nearest-even fp32 -> bf16 (finite inputs)
  unsigned int x = __float_as_uint(f);
  unsigned int lsb = (x >> 16) & 1u;
  x += 0x7fffu + lsb;
  return (u16)(x >> 16);
}

// ---------------------------------------------------------------------------
// GEMM: C[M,N] = A[M,K] @ B[N,K]^T (+bias[col]) (+addend[row,col])
// A,B bf16 (raw u16) row-major with lda/ldb strides; C fp32 with stride N.
// Block 256 threads = 4 waves; block tile 128x128, BK=32.
// mfma_f32_16x16x32_bf16 layouts (HW-verified m89/m91):
//   A frag: A[m=lane&15][k=(lane>>4)*8+j], 8 contiguous bf16
//   B frag: B[k][n]=W[n=lane&15][k=(lane>>4)*8+j], 8 contiguous bf16 of W row
//   C/D:    col=lane&15, row=(lane>>4)*4+reg
// ---------------------------------------------------------------------------
struct GArg {
  const u16* A; int lda; int K;
  const u16* B; int ldb;
  float* C;
  const float* bias;    // nullable
  const float* addend;  // nullable, stride N
};

#define BM 128
#define BN 128
#define BK 32
#define LDSS 40   // padded LDS stride (elements): 80B rows -> 2-way max conflict (free)

__global__ __launch_bounds__(256, 2) void gemm_bt2(GArg ga, GArg gb, int N)
{
  GArg g = (blockIdx.z == 0) ? ga : gb;
  __shared__ __align__(16) u16 As[BM * LDSS];
  __shared__ __align__(16) u16 Bs[BN * LDSS];

  const int tid  = threadIdx.x;
  const int wave = tid >> 6;
  const int lane = tid & 63;
  const int q    = lane >> 4;
  const int l16  = lane & 15;
  const int waveRow = (wave >> 1) * 64;
  const int waveCol = (wave & 1) * 64;
  const int rowBase = blockIdx.y * BM;
  const int colBase = blockIdx.x * BN;

  f32x4 acc[4][4];
  #pragma unroll
  for (int i = 0; i < 4; ++i)
    #pragma unroll
    for (int j = 0; j < 4; ++j)
      acc[i][j] = (f32x4){0.f, 0.f, 0.f, 0.f};

  for (int k0 = 0; k0 < g.K; k0 += BK) {
    __syncthreads();
    // stage A and B tiles: 128x32 bf16 each, 16B per thread per iter
    #pragma unroll
    for (int it = 0; it < 2; ++it) {
      int li = it * 2048 + tid * 8;
      int r = li >> 5, c = li & 31;
      *(float4*)&As[r * LDSS + c] =
          *(const float4*)(g.A + (size_t)(rowBase + r) * g.lda + k0 + c);
      *(float4*)&Bs[r * LDSS + c] =
          *(const float4*)(g.B + (size_t)(colBase + r) * g.ldb + k0 + c);
    }
    __syncthreads();

    bf16x8 af[4], bfr[4];
    #pragma unroll
    for (int mi = 0; mi < 4; ++mi)
      af[mi] = *(const bf16x8*)&As[(waveRow + mi * 16 + l16) * LDSS + q * 8];
    #pragma unroll
    for (int ni = 0; ni < 4; ++ni)
      bfr[ni] = *(const bf16x8*)&Bs[(waveCol + ni * 16 + l16) * LDSS + q * 8];
    #pragma unroll
    for (int mi = 0; mi < 4; ++mi)
      #pragma unroll
      for (int ni = 0; ni < 4; ++ni)
        acc[mi][ni] = __builtin_amdgcn_mfma_f32_16x16x32_bf16(af[mi], bfr[ni], acc[mi][ni], 0, 0, 0);
  }

  #pragma unroll
  for (int mi = 0; mi < 4; ++mi) {
    #pragma unroll
    for (int ni = 0; ni < 4; ++ni) {
      #pragma unroll
      for (int r = 0; r < 4; ++r) {
        int row = rowBase + waveRow + mi * 16 + q * 4 + r;
        int col = colBase + waveCol + ni * 16 + l16;
        float v = acc[mi][ni][r];
        if (g.bias)   v += g.bias[col];
        if (g.addend) v += g.addend[(size_t)row * N + col];
        g.C[(size_t)row * N + col] = v;
      }
    }
  }
}

// ---------------------------------------------------------------------------
// GRU gate nonlinearity: hn = (1-z)*n + z*h, updates h (fp32) + bf16 copy
// ---------------------------------------------------------------------------
__global__ void gate_kernel(const float* __restrict__ GI, const float* __restrict__ GH,
                            float* __restrict__ h, u16* __restrict__ hbf)
{
  int idx = blockIdx.x * blockDim.x + threadIdx.x;   // BS*H = 1M
  int b = idx >> 10, m = idx & 1023;
  size_t base = (size_t)b * N3H;
  float gir = GI[base + m], giz = GI[base + HH + m], gin = GI[base + 2 * HH + m];
  float ghr = GH[base + m], ghz = GH[base + HH + m], ghn = GH[base + 2 * HH + m];
  float r = 1.f / (1.f + expf(-(gir + ghr)));
  float z = 1.f / (1.f + expf(-(giz + ghz)));
  float n = tanhf(gin + r * ghn);
  float hv = h[idx];
  float hn = (1.f - z) * n + z * hv;
  h[idx]   = hn;
  hbf[idx] = f2bf(hn);
}

// ---------------------------------------------------------------------------
// Output head activation: softmax[0:32], softmax[32:47], sigmoid[47:256]
// One block per batch row; writes fp32 output + bf16 x for next step.
// ---------------------------------------------------------------------------
__global__ void act_kernel(const float* __restrict__ logits,
                           float* __restrict__ out, u16* __restrict__ xbf, int t)
{
  int b = blockIdx.x;      // 1024
  int d = threadIdx.x;     // 256
  __shared__ float sv[DD];
  float v = logits[(size_t)b * DD + d];
  sv[d] = v;
  __syncthreads();
  float res;
  if (d < CAT1) {
    float m = -1e30f;
    for (int j = 0; j < CAT1; ++j) m = fmaxf(m, sv[j]);
    float s = 0.f;
    for (int j = 0; j < CAT1; ++j) s += expf(sv[j] - m);
    res = expf(v - m) / s;
  } else if (d < CAT2E) {
    float m = -1e30f;
    for (int j = CAT1; j < CAT2E; ++j) m = fmaxf(m, sv[j]);
    float s = 0.f;
    for (int j = CAT1; j < CAT2E; ++j) s += expf(sv[j] - m);
    res = expf(v - m) / s;
  } else {
    res = 1.f / (1.f + expf(-v));
  }
  out[((size_t)b * TT + t) * DD + d] = res;   // fp32 output (reference dtype)
  xbf[b * DD + d] = f2bf(res);                // bf16 copy feeds next step's GEMM
}

// ---------------------------------------------------------------------------
// Prep: fp32 -> bf16 weight conversion; state init from embed/dynamics
// ---------------------------------------------------------------------------
__global__ void convert_kernel(const float* __restrict__ src, u16* __restrict__ dst, int n)
{
  int i = blockIdx.x * blockDim.x + threadIdx.x;
  if (i < n) dst[i] = f2bf(src[i]);
}

__global__ void prep_state(const float* __restrict__ embed, const float* __restrict__ dyn,
                           u16* __restrict__ globbf,
                           float* __restrict__ h0, u16* __restrict__ h0bf,
                           float* __restrict__ h1, u16* __restrict__ h1bf,
                           u16* __restrict__ xbf)
{
  int idx = blockIdx.x * blockDim.x + threadIdx.x;  // 1M
  int b = idx >> 10, j = idx & 1023;
  const float* e = embed + (size_t)b * 3072;
  globbf[idx] = f2bf(e[j]);
  float v0 = e[1024 + j]; h0[idx] = v0; h0bf[idx] = f2bf(v0);
  float v1 = e[2048 + j]; h1[idx] = v1; h1bf[idx] = f2bf(v1);
  if (j < DD) {
    xbf[b * DD + j] = f2bf(dyn[(size_t)b * (TT * DD) + j]);  // x0 = dynamics[:,0,:]
  }
}

// ---------------------------------------------------------------------------
extern "C" void kernel_launch(void* const* d_in, const int* in_sizes, int n_in,
                              void* d_out, int out_size, void* d_ws, size_t ws_size,
                              hipStream_t stream)
{
  const float* embed = (const float*)d_in[0];
  const float* dyn   = (const float*)d_in[1];
  // d_in[2] = seq_len (256, hardcoded)
  const float* W_ih0 = (const float*)d_in[3];
  const float* W_hh0 = (const float*)d_in[4];
  const float* b_ih0 = (const float*)d_in[5];
  const float* b_hh0 = (const float*)d_in[6];
  const float* W_ih1 = (const float*)d_in[7];
  const float* W_hh1 = (const float*)d_in[8];
  const float* b_ih1 = (const float*)d_in[9];
  const float* b_hh1 = (const float*)d_in[10];
  const float* W_fc  = (const float*)d_in[11];
  const float* b_fc  = (const float*)d_in[12];
  float* out = (float*)d_out;   // reference output dtype is float32

  // workspace carve (256B aligned)
  char* ws = (char*)d_ws;
  size_t off = 0;
  auto carve = [&](size_t bytes) -> void* {
    void* p = ws + off;
    off += (bytes + 255) & ~(size_t)255;
    return p;
  };
  u16* Wih0b = (u16*)carve((size_t)N3H * 1280 * 2);
  u16* Whh0b = (u16*)carve((size_t)N3H * HH * 2);
  u16* Wih1b = (u16*)carve((size_t)N3H * HH * 2);
  u16* Whh1b = (u16*)carve((size_t)N3H * HH * 2);
  u16* Wfcb  = (u16*)carve((size_t)DD * HH * 2);
  u16* globb = (u16*)carve((size_t)BSB * HH * 2);
  u16* xbf   = (u16*)carve((size_t)BSB * DD * 2);
  float* h0f = (float*)carve((size_t)BSB * HH * 4);
  float* h1f = (float*)carve((size_t)BSB * HH * 4);
  u16* h0b   = (u16*)carve((size_t)BSB * HH * 2);
  u16* h1b   = (u16*)carve((size_t)BSB * HH * 2);
  float* Gglob  = (float*)carve((size_t)BSB * N3H * 4);
  float* GI     = (float*)carve((size_t)BSB * N3H * 4);
  float* GHb    = (float*)carve((size_t)BSB * N3H * 4);
  float* logits = (float*)carve((size_t)BSB * DD * 4);
  (void)ws_size;

  // --- prep: weight conversion ---
  {
    int n;
    n = N3H * 1280; convert_kernel<<<(n + 255) / 256, 256, 0, stream>>>(W_ih0, Wih0b, n);
    n = N3H * HH;   convert_kernel<<<(n + 255) / 256, 256, 0, stream>>>(W_hh0, Whh0b, n);
    n = N3H * HH;   convert_kernel<<<(n + 255) / 256, 256, 0, stream>>>(W_ih1, Wih1b, n);
    n = N3H * HH;   convert_kernel<<<(n + 255) / 256, 256, 0, stream>>>(W_hh1, Whh1b, n);
    n = DD * HH;    convert_kernel<<<(n + 255) / 256, 256, 0, stream>>>(W_fc, Wfcb, n);
  }
  prep_state<<<(BSB * HH) / 256, 256, 0, stream>>>(embed, dyn, globb, h0f, h0b, h1f, h1b, xbf);

  // --- precompute Gglob = glob @ W_ih0[:, :H]^T + b_ih0  [BS, 3H] ---
  {
    GArg g{globb, HH, HH, Wih0b, 1280, Gglob, b_ih0, nullptr};
    gemm_bt2<<<dim3(N3H / BN, BSB / BM, 1), 256, 0, stream>>>(g, g, N3H);
  }

  // --- T sequential steps ---
  for (int t = 0; t < TT; ++t) {
    // layer 0: GI = Gglob + x @ W_ih0[:, H:]^T ; GH = h0 @ W_hh0^T + b_hh0
    {
      GArg gi{xbf, DD, DD, Wih0b + HH, 1280, GI, nullptr, Gglob};
      GArg gh{h0b, HH, HH, Whh0b, HH, GHb, b_hh0, nullptr};
      gemm_bt2<<<dim3(N3H / BN, BSB / BM, 2), 256, 0, stream>>>(gi, gh, N3H);
    }
    gate_kernel<<<(BSB * HH) / 256, 256, 0, stream>>>(GI, GHb, h0f, h0b);

    // layer 1: GI = h0n @ W_ih1^T + b_ih1 ; GH = h1 @ W_hh1^T + b_hh1
    {
      GArg gi{h0b, HH, HH, Wih1b, HH, GI, b_ih1, nullptr};
      GArg gh{h1b, HH, HH, Whh1b, HH, GHb, b_hh1, nullptr};
      gemm_bt2<<<dim3(N3H / BN, BSB / BM, 2), 256, 0, stream>>>(gi, gh, N3H);
    }
    gate_kernel<<<(BSB * HH) / 256, 256, 0, stream>>>(GI, GHb, h1f, h1b);

    // head: logits = h1n @ W_fc^T + b_fc ; activation -> out[:, t, :] and next x
    {
      GArg g{h1b, HH, HH, Wfcb, HH, logits, b_fc, nullptr};
      gemm_bt2<<<dim3(DD / BN, BSB / BM, 1), 256, 0, stream>>>(g, g, DD);
    }
    act_kernel<<<BSB, DD, 0, stream>>>(logits, out, xbf, t);
  }
}